// Round 7
// baseline (217.777 us; speedup 1.0000x reference)
//
#include <hip/hip_runtime.h>
#include <hip/hip_bf16.h>

#define NCLS 345
#define CPAD 384
#define DIM  512
#define BCAP 256
#define NSTEP 16            // DIM / 32

typedef float f32x4 __attribute__((ext_vector_type(4)));
typedef short s16x8 __attribute__((ext_vector_type(8)));
typedef unsigned long long u64;

__device__ __forceinline__ short f2bf(float f) {
  union { float f; unsigned u; } v; v.f = f;
  unsigned r = v.u + 0x7fffu + ((v.u >> 16) & 1u);   // RNE
  return (short)(r >> 16);
}

__device__ __forceinline__ short f2bf_n(float f) {
  __hip_bfloat16 b = __float2bfloat16(f);             // RNE; pairs to v_cvt_pk_bf16_f32
  union { __hip_bfloat16 b; short s; } u; u.b = b; return u.s;
}

// ---- Stage 1: one pass over N, bucket (ent_bits<<32)|idx per class ----
__global__ __launch_bounds__(256) void scan_classes(
    const float* __restrict__ ent, const int* __restrict__ y_hat,
    u64* __restrict__ bucket, int* __restrict__ cnt, int N)
{
  int i = blockIdx.x * 256 + threadIdx.x;
  if (i >= N) return;
  int c = y_hat[i];
  unsigned eb = __float_as_uint(ent[i]);
  u64 key = ((u64)eb << 32) | (unsigned)i;
  int p = atomicAdd(&cnt[c], 1);
  if (p < BCAP) bucket[(size_t)c * BCAP + p] = key;
}

// ---- Stage 2: per-class select (exact stable rank) + normalized-row sum ----
__global__ __launch_bounds__(512) void select_accum(
    const float* __restrict__ supports, const u64* __restrict__ bucket,
    const int* __restrict__ cnt, const int* __restrict__ fKp,
    short* __restrict__ Wt)
{
  const int c = blockIdx.x;
  const int tid = threadIdx.x;
  const int lane = tid & 63, w = tid >> 6;
  __shared__ u64   s_key[BCAP];
  __shared__ int   s_selidx[BCAP];
  __shared__ int   s_nsel;
  __shared__ float s_part[8][DIM];   // 16 KB
  __shared__ float s_red[8];
  if (tid == 0) s_nsel = 0;
  const int S = (c < NCLS) ? min(cnt[c], BCAP) : 0;
  const int K = fKp[0];
  for (int e = tid; e < S; e += 512) s_key[e] = bucket[(size_t)c * BCAP + e];
  __syncthreads();
  for (int e = tid; e < S; e += 512) {
    u64 ke = s_key[e];
    int r = 0;
    for (int j = 0; j < S; ++j) r += (s_key[j] < ke) ? 1 : 0;
    if (r < K) { int p = atomicAdd(&s_nsel, 1); s_selidx[p] = (int)(unsigned)(ke & 0xffffffffull); }
  }
  __syncthreads();
  const int nsel = s_nsel;
  f32x4 p0 = {0.f,0.f,0.f,0.f}, p1 = {0.f,0.f,0.f,0.f};
  for (int e0 = w; e0 < nsel; e0 += 16) {
    const int e1 = e0 + 8;
    const bool h1 = (e1 < nsel);
    const f32x4* r0 = (const f32x4*)(supports + (size_t)s_selidx[e0] * DIM);
    f32x4 a0 = r0[lane], a1 = r0[lane + 64];
    f32x4 b0 = {0.f,0.f,0.f,0.f}, b1 = {0.f,0.f,0.f,0.f};
    if (h1) {
      const f32x4* r1 = (const f32x4*)(supports + (size_t)s_selidx[e1] * DIM);
      b0 = r1[lane]; b1 = r1[lane + 64];
    }
    float s0 = 0.f, s1 = 0.f;
#pragma unroll
    for (int j = 0; j < 4; ++j) {
      s0 = fmaf(a0[j], a0[j], s0); s0 = fmaf(a1[j], a1[j], s0);
      s1 = fmaf(b0[j], b0[j], s1); s1 = fmaf(b1[j], b1[j], s1);
    }
#pragma unroll
    for (int off = 32; off; off >>= 1) { s0 += __shfl_xor(s0, off); s1 += __shfl_xor(s1, off); }
    float c0 = 1.f / fmaxf(sqrtf(s0), 1e-12f);
    float c1 = 1.f / fmaxf(sqrtf(s1), 1e-12f);
#pragma unroll
    for (int j = 0; j < 4; ++j) { p0[j] = fmaf(a0[j], c0, p0[j]); p1[j] = fmaf(a1[j], c0, p1[j]); }
    if (h1) {
#pragma unroll
      for (int j = 0; j < 4; ++j) { p0[j] = fmaf(b0[j], c1, p0[j]); p1[j] = fmaf(b1[j], c1, p1[j]); }
    }
  }
  *(f32x4*)&s_part[w][lane * 4]       = p0;
  *(f32x4*)&s_part[w][256 + lane * 4] = p1;
  __syncthreads();
  float acc = 0.f;
#pragma unroll
  for (int ww = 0; ww < 8; ++ww) acc += s_part[ww][tid];
  float sq = acc * acc;
#pragma unroll
  for (int off = 32; off; off >>= 1) sq += __shfl_xor(sq, off);
  if (lane == 0) s_red[w] = sq;
  __syncthreads();
  float tot = 0.f;
#pragma unroll
  for (int ww = 0; ww < 8; ++ww) tot += s_red[ww];
  float sc = 1.f / fmaxf(sqrtf(tot), 1e-12f);
  Wt[(size_t)c * DIM + tid] = f2bf(acc * sc);
}

// ---- Kernel B: out[M,345] = z[M,512] @ W ----
// BM=32 x BN=384 (z read once). BK=32, B double-buffered in LDS (2x24KB),
// staged via global_load_lds (counted vmcnt(4), never 0, one barrier/step).
// A is wave-private: global->reg distance-1 prefetch, no LDS, no barrier dep.
// 8 waves split cols (48 each). Epilogue: LDS C-blob -> flat coalesced copy.
__global__ __launch_bounds__(512, 4) void gemm_zw(
    const float* __restrict__ z, const short* __restrict__ Wt,
    float* __restrict__ out)
{
  __shared__ __align__(16) char lds[49152];     // 2 x 24KB B dbuf; reused for C blob
  const int tid  = threadIdx.x;
  const int lane = tid & 63;
  const int w    = tid >> 6;                    // wave 0..7 = col group
  const int bm   = blockIdx.x;
  const int fr   = lane & 15, fq = lane >> 4;
  const int Mbase = bm * 32;

  // A: wave-private fragment loads (rows mt*16+fr, k-slot fq*8)
  const float* pa0 = z + (size_t)(Mbase + fr) * DIM + fq * 8;
  const float* pa1 = pa0 + (size_t)16 * DIM;

  // B stage: 24 chunks of 1KB per step; wave w owns chunks w*3..w*3+2.
  // LDS row r (64B) <- global row r, k-run ks*64, slot swizzled by (r>>1)&3.
  const char* Wb = (const char*)Wt;
  const char* gsrc[3];
  int loff[3];
#pragma unroll
  for (int i = 0; i < 3; ++i) {
    const int c = w * 3 + i;
    const int r = c * 16 + (lane >> 2);
    const int s = lane & 3;
    gsrc[i] = Wb + (size_t)r * (DIM * 2) + (((unsigned)(s ^ ((r >> 1) & 3))) << 4);
    loff[i] = c * 1024;
  }

  // B fragment read offsets: row r = w*48 + nt*16 + fr, slot fq ^ ((r>>1)&3)
  unsigned roB[3];
#pragma unroll
  for (int nt = 0; nt < 3; ++nt) {
    const int r = w * 48 + nt * 16 + fr;
    roB[nt] = (unsigned)(r * 64) + (((unsigned)(fq ^ ((r >> 1) & 3))) << 4);
  }

  f32x4 acc[2][3];
#pragma unroll
  for (int mt = 0; mt < 2; ++mt)
#pragma unroll
    for (int nt = 0; nt < 3; ++nt) acc[mt][nt] = f32x4{0.f, 0.f, 0.f, 0.f};

#define STAGE(P, KS)                                                             \
  {                                                                              \
    _Pragma("unroll")                                                            \
    for (int i = 0; i < 3; ++i)                                                  \
      __builtin_amdgcn_global_load_lds(                                          \
          (const __attribute__((address_space(1))) unsigned int*)(gsrc[i] + (KS) * 64), \
          (__attribute__((address_space(3))) unsigned int*)(lds + (P) * 24576 + loff[i]), \
          16, 0, 0);                                                             \
  }
#define LOADA(P, KS)                                                             \
  {                                                                              \
    av[P][0][0] = *(const f32x4*)(pa0 + (KS) * 32);                              \
    av[P][0][1] = *(const f32x4*)(pa0 + (KS) * 32 + 4);                          \
    av[P][1][0] = *(const f32x4*)(pa1 + (KS) * 32);                              \
    av[P][1][1] = *(const f32x4*)(pa1 + (KS) * 32 + 4);                          \
  }

  f32x4 av[2][2][2];   // [parity][mt][half]

  // prologue: B(0) + A(0); drain B(0) (A(0) waited by compiler at use)
  STAGE(0, 0);
  LOADA(0, 0);
  asm volatile("s_waitcnt vmcnt(4)" ::: "memory");
  __builtin_amdgcn_sched_barrier(0);
  __builtin_amdgcn_s_barrier();

#pragma unroll
  for (int t = 0; t < NSTEP; ++t) {
    const int p = t & 1;
    if (t < NSTEP - 1) {               // issue next step's B (to LDS) + A (to regs)
      STAGE(p ^ 1, t + 1);
      LOADA(p ^ 1, t + 1);
    }
    s16x8 a16[2];
#pragma unroll
    for (int mt = 0; mt < 2; ++mt)
#pragma unroll
      for (int j = 0; j < 4; ++j) {
        a16[mt][j]     = f2bf_n(av[p][mt][0][j]);
        a16[mt][4 + j] = f2bf_n(av[p][mt][1][j]);
      }
    s16x8 bf[3];
#pragma unroll
    for (int nt = 0; nt < 3; ++nt)
      bf[nt] = *(const s16x8*)(lds + p * 24576 + roB[nt]);
    __builtin_amdgcn_s_setprio(1);
#pragma unroll
    for (int nt = 0; nt < 3; ++nt)
#pragma unroll
      for (int mt = 0; mt < 2; ++mt)
        acc[mt][nt] = __builtin_amdgcn_mfma_f32_16x16x32_bf16(bf[nt], a16[mt], acc[mt][nt], 0, 0, 0);
    __builtin_amdgcn_s_setprio(0);
    if (t < NSTEP - 1) {
      // counted wait: drains B(t+1) (oldest 3), leaves A(t+1)'s 4 loads in flight
      asm volatile("s_waitcnt vmcnt(4)" ::: "memory");
      __builtin_amdgcn_sched_barrier(0);
      asm volatile("s_waitcnt lgkmcnt(0)" ::: "memory");
      __builtin_amdgcn_s_barrier();
    }
  }
#undef STAGE
#undef LOADA

  // ---- epilogue: acc -> LDS C blob (exact [32][345] f32 layout) ----
  __syncthreads();                      // full drain; safe to overwrite B buffers
#pragma unroll
  for (int mt = 0; mt < 2; ++mt) {
    const int row = mt * 16 + fr;
#pragma unroll
    for (int nt = 0; nt < 3; ++nt) {
      const int colb = w * 48 + nt * 16 + fq * 4;
#pragma unroll
      for (int j = 0; j < 4; ++j) {
        const int col = colb + j;
        if (col < NCLS) *(float*)(lds + (((size_t)row * NCLS + col) << 2)) = acc[mt][nt][j];
      }
    }
  }
  __syncthreads();
  // flat coalesced copy: 32*345*4 = 44160 B = 2760 x 16B
  char* dst = (char*)(out + (size_t)Mbase * NCLS);
  for (int c = tid; c < 2760; c += 512) {
    f32x4 v = *(const f32x4*)(lds + c * 16);
    *(f32x4*)(dst + c * 16) = v;
  }
}

extern "C" void kernel_launch(void* const* d_in, const int* in_sizes, int n_in,
                              void* d_out, int out_size, void* d_ws, size_t ws_size,
                              hipStream_t stream) {
  const float* z        = (const float*)d_in[0];
  const float* supports = (const float*)d_in[1];
  const float* ent      = (const float*)d_in[2];
  const int*   y_hat    = (const int*)d_in[3];
  const int*   fK       = (const int*)d_in[4];
  float* out = (float*)d_out;
  short* Wt  = (short*)d_ws;
  const int N = in_sizes[2];
  const int M = in_sizes[0] / DIM;

  const size_t offC = (size_t)CPAD * DIM * 2;          // 393216
  const size_t offB = offC + 2048;
  int* cnt    = (int*)((char*)d_ws + offC);
  u64* bucket = (u64*)((char*)d_ws + offB);
  hipMemsetAsync(cnt, 0, CPAD * sizeof(int), stream);
  scan_classes<<<dim3((N + 255) / 256), dim3(256), 0, stream>>>(ent, y_hat, bucket, cnt, N);
  select_accum<<<dim3(CPAD), dim3(512), 0, stream>>>(supports, bucket, cnt, fK, Wt);
  gemm_zw<<<dim3(M / 32), dim3(512), 0, stream>>>(z, Wt, out);
}

// Round 8
// 139.910 us; speedup vs baseline: 1.5566x; 1.5566x over previous
//
#include <hip/hip_runtime.h>
#include <hip/hip_bf16.h>

#define NCLS 345
#define CPAD 384
#define DIM  512
#define BCAP 256

typedef float f32x4 __attribute__((ext_vector_type(4)));
typedef short s16x8 __attribute__((ext_vector_type(8)));
typedef unsigned long long u64;

__device__ __forceinline__ short f2bf(float f) {
  union { float f; unsigned u; } v; v.f = f;
  unsigned r = v.u + 0x7fffu + ((v.u >> 16) & 1u);   // RNE
  return (short)(r >> 16);
}

__device__ __forceinline__ short f2bf_n(float f) {
  __hip_bfloat16 b = __float2bfloat16(f);             // RNE; pairs to v_cvt_pk_bf16_f32
  union { __hip_bfloat16 b; short s; } u; u.b = b; return u.s;
}

// ---- Stage 1: one pass over N, bucket (ent_bits<<32)|idx per class ----
__global__ __launch_bounds__(256) void scan_classes(
    const float* __restrict__ ent, const int* __restrict__ y_hat,
    u64* __restrict__ bucket, int* __restrict__ cnt, int N)
{
  int i = blockIdx.x * 256 + threadIdx.x;
  if (i >= N) return;
  int c = y_hat[i];
  unsigned eb = __float_as_uint(ent[i]);
  u64 key = ((u64)eb << 32) | (unsigned)i;
  int p = atomicAdd(&cnt[c], 1);
  if (p < BCAP) bucket[(size_t)c * BCAP + p] = key;
}

// ---- Stage 2: per-class select + normalized-row sum, emit FRAGMENT-PACKED W ----
// Packed layout: frag(kt 0..15, ct 0..23) of 1024B; lane = fq*16+fr holds
// W[col = ct*16+fr][k = kt*32+fq*8+j], j=0..7. One dwordx4 wave-load = one frag.
__global__ __launch_bounds__(512) void select_accum(
    const float* __restrict__ supports, const u64* __restrict__ bucket,
    const int* __restrict__ cnt, const int* __restrict__ fKp,
    short* __restrict__ Wp)
{
  const int c = blockIdx.x;
  const int tid = threadIdx.x;
  const int lane = tid & 63, w = tid >> 6;
  __shared__ u64   s_key[BCAP];
  __shared__ int   s_selidx[BCAP];
  __shared__ int   s_nsel;
  __shared__ float s_part[8][DIM];   // 16 KB
  __shared__ float s_red[8];
  if (tid == 0) s_nsel = 0;
  const int S = (c < NCLS) ? min(cnt[c], BCAP) : 0;
  const int K = fKp[0];
  for (int e = tid; e < S; e += 512) s_key[e] = bucket[(size_t)c * BCAP + e];
  __syncthreads();
  for (int e = tid; e < S; e += 512) {
    u64 ke = s_key[e];
    int r = 0;
    for (int j = 0; j < S; ++j) r += (s_key[j] < ke) ? 1 : 0;
    if (r < K) { int p = atomicAdd(&s_nsel, 1); s_selidx[p] = (int)(unsigned)(ke & 0xffffffffull); }
  }
  __syncthreads();
  const int nsel = s_nsel;
  f32x4 p0 = {0.f,0.f,0.f,0.f}, p1 = {0.f,0.f,0.f,0.f};
  for (int e0 = w; e0 < nsel; e0 += 16) {
    const int e1 = e0 + 8;
    const bool h1 = (e1 < nsel);
    const f32x4* r0 = (const f32x4*)(supports + (size_t)s_selidx[e0] * DIM);
    f32x4 a0 = r0[lane], a1 = r0[lane + 64];
    f32x4 b0 = {0.f,0.f,0.f,0.f}, b1 = {0.f,0.f,0.f,0.f};
    if (h1) {
      const f32x4* r1 = (const f32x4*)(supports + (size_t)s_selidx[e1] * DIM);
      b0 = r1[lane]; b1 = r1[lane + 64];
    }
    float s0 = 0.f, s1 = 0.f;
#pragma unroll
    for (int j = 0; j < 4; ++j) {
      s0 = fmaf(a0[j], a0[j], s0); s0 = fmaf(a1[j], a1[j], s0);
      s1 = fmaf(b0[j], b0[j], s1); s1 = fmaf(b1[j], b1[j], s1);
    }
#pragma unroll
    for (int off = 32; off; off >>= 1) { s0 += __shfl_xor(s0, off); s1 += __shfl_xor(s1, off); }
    float c0 = 1.f / fmaxf(sqrtf(s0), 1e-12f);
    float c1 = 1.f / fmaxf(sqrtf(s1), 1e-12f);
#pragma unroll
    for (int j = 0; j < 4; ++j) { p0[j] = fmaf(a0[j], c0, p0[j]); p1[j] = fmaf(a1[j], c0, p1[j]); }
    if (h1) {
#pragma unroll
      for (int j = 0; j < 4; ++j) { p0[j] = fmaf(b0[j], c1, p0[j]); p1[j] = fmaf(b1[j], c1, p1[j]); }
    }
  }
  *(f32x4*)&s_part[w][lane * 4]       = p0;
  *(f32x4*)&s_part[w][256 + lane * 4] = p1;
  __syncthreads();
  float acc = 0.f;
#pragma unroll
  for (int ww = 0; ww < 8; ++ww) acc += s_part[ww][tid];
  float sq = acc * acc;
#pragma unroll
  for (int off = 32; off; off >>= 1) sq += __shfl_xor(sq, off);
  if (lane == 0) s_red[w] = sq;
  __syncthreads();
  float tot = 0.f;
#pragma unroll
  for (int ww = 0; ww < 8; ++ww) tot += s_red[ww];
  float sc = 1.f / fmaxf(sqrtf(tot), 1e-12f);
  // fragment-packed store: k = tid
  {
    const int k = tid;
    const int kt = k >> 5, fq = (k >> 3) & 3, j = k & 7;
    const int ct = c >> 4, fr = c & 15;
    const size_t pos = (size_t)(kt * 24 + ct) * 512 + fq * 128 + fr * 8 + j;
    Wp[pos] = f2bf(acc * sc);
  }
}

// ---- Kernel B: out[M,345] = z[M,512] @ W ----
// Zero-LDS, zero-barrier main loop. Each of 4 waves owns 64 rows x 96 cols.
// B: fragment-packed W -> one coalesced dwordx4 per fragment (L2-resident).
// A: z fragments coalesced from global (L3-resident), distance-1 prefetch.
// Epilogue: acc -> 32-row LDS C-blob halves -> flat coalesced dwordx4 copy.
__global__ __launch_bounds__(256, 2) void gemm_zw(
    const float* __restrict__ z, const short* __restrict__ Wp,
    float* __restrict__ out)
{
  __shared__ __align__(16) char lds[44160];      // 32 rows x 345 f32
  const int tid  = threadIdx.x;
  const int lane = tid & 63;
  const int w    = tid >> 6;                     // wave 0..3 = 96-col group
  const int fr   = lane & 15, fq = lane >> 4;
  const int Mbase = blockIdx.x * 64;

  // A: per (mt,kt): lane reads z[Mbase+mt*16+fr][kt*32+fq*8 .. +7] as 2 f32x4
  const char* pa = (const char*)z + (size_t)(Mbase + fr) * 2048 + fq * 32;
  // B: per (nt,kt): frag index kt*24 + w*6 + nt, lane*16 bytes within frag
  const char* pb = (const char*)Wp + (size_t)w * 6 * 1024 + (size_t)lane * 16;

  f32x4 acc[4][6];
#pragma unroll
  for (int mt = 0; mt < 4; ++mt)
#pragma unroll
    for (int nt = 0; nt < 6; ++nt) acc[mt][nt] = f32x4{0.f, 0.f, 0.f, 0.f};

  f32x4 A0[4][2], A1[4][2];
  s16x8 B0[6], B1[6];

  // prologue: t=0
#pragma unroll
  for (int mt = 0; mt < 4; ++mt) {
    A0[mt][0] = *(const f32x4*)(pa + mt * 32768);
    A0[mt][1] = *(const f32x4*)(pa + mt * 32768 + 16);
  }
#pragma unroll
  for (int nt = 0; nt < 6; ++nt)
    B0[nt] = *(const s16x8*)(pb + nt * 1024);

#pragma unroll
  for (int t = 0; t < 16; ++t) {
    if (t < 15) {   // issue next tile's loads first (latency covered by cvt+MFMA)
#pragma unroll
      for (int mt = 0; mt < 4; ++mt) {
        A1[mt][0] = *(const f32x4*)(pa + mt * 32768 + (t + 1) * 128);
        A1[mt][1] = *(const f32x4*)(pa + mt * 32768 + (t + 1) * 128 + 16);
      }
#pragma unroll
      for (int nt = 0; nt < 6; ++nt)
        B1[nt] = *(const s16x8*)(pb + (size_t)(t + 1) * 24576 + nt * 1024);
    }
    s16x8 a16[4];
#pragma unroll
    for (int mt = 0; mt < 4; ++mt)
#pragma unroll
      for (int j = 0; j < 4; ++j) {
        a16[mt][j]     = f2bf_n(A0[mt][0][j]);
        a16[mt][4 + j] = f2bf_n(A0[mt][1][j]);
      }
#pragma unroll
    for (int nt = 0; nt < 6; ++nt)
#pragma unroll
      for (int mt = 0; mt < 4; ++mt)
        acc[mt][nt] = __builtin_amdgcn_mfma_f32_16x16x32_bf16(B0[nt], a16[mt], acc[mt][nt], 0, 0, 0);
    if (t < 15) {
#pragma unroll
      for (int mt = 0; mt < 4; ++mt) { A0[mt][0] = A1[mt][0]; A0[mt][1] = A1[mt][1]; }
#pragma unroll
      for (int nt = 0; nt < 6; ++nt) B0[nt] = B1[nt];
    }
  }

  // ---- epilogue: two 32-row halves through the LDS C-blob ----
#pragma unroll
  for (int h = 0; h < 2; ++h) {
    __syncthreads();                     // blob free (h=0: first use; h=1: copy done)
#pragma unroll
    for (int ml = 0; ml < 2; ++ml) {
      const int rl = ml * 16 + fr;       // local row 0..31
      const int mt = h * 2 + ml;
#pragma unroll
      for (int nt = 0; nt < 6; ++nt) {
        const int colb = w * 96 + nt * 16 + fq * 4;
#pragma unroll
        for (int j = 0; j < 4; ++j) {
          const int col = colb + j;
          if (col < NCLS)
            *(float*)(lds + (((size_t)rl * NCLS + col) << 2)) = acc[mt][nt][j];
        }
      }
    }
    __syncthreads();
    // flat coalesced copy: 32*345*4 = 44160 B = 2760 x 16B
    char* dst = (char*)(out + (size_t)(Mbase + h * 32) * NCLS);
    for (int c = tid; c < 2760; c += 256) {
      f32x4 v = *(const f32x4*)(lds + c * 16);
      *(f32x4*)(dst + c * 16) = v;
    }
  }
}

extern "C" void kernel_launch(void* const* d_in, const int* in_sizes, int n_in,
                              void* d_out, int out_size, void* d_ws, size_t ws_size,
                              hipStream_t stream) {
  const float* z        = (const float*)d_in[0];
  const float* supports = (const float*)d_in[1];
  const float* ent      = (const float*)d_in[2];
  const int*   y_hat    = (const int*)d_in[3];
  const int*   fK       = (const int*)d_in[4];
  float* out = (float*)d_out;
  short* Wp  = (short*)d_ws;           // fragment-packed W, 384 KB
  const int N = in_sizes[2];
  const int M = in_sizes[0] / DIM;

  const size_t offC = (size_t)CPAD * DIM * 2;          // 393216
  const size_t offB = offC + 2048;
  int* cnt    = (int*)((char*)d_ws + offC);
  u64* bucket = (u64*)((char*)d_ws + offB);
  hipMemsetAsync(cnt, 0, CPAD * sizeof(int), stream);
  scan_classes<<<dim3((N + 255) / 256), dim3(256), 0, stream>>>(ent, y_hat, bucket, cnt, N);
  select_accum<<<dim3(CPAD), dim3(512), 0, stream>>>(supports, bucket, cnt, fK, Wp);
  gemm_zw<<<dim3(M / 64), dim3(256), 0, stream>>>(z, Wp, out);
}

// Round 9
// 98.501 us; speedup vs baseline: 2.2109x; 1.4204x over previous
//
#include <hip/hip_runtime.h>
#include <hip/hip_bf16.h>

#define NCLS 345
#define CPAD 384
#define DIM  512
#define BCAP 256

typedef float f32x4 __attribute__((ext_vector_type(4)));
typedef short s16x8 __attribute__((ext_vector_type(8)));
typedef short s16x4 __attribute__((ext_vector_type(4)));
typedef unsigned long long u64;

__device__ __forceinline__ short f2bf(float f) {
  union { float f; unsigned u; } v; v.f = f;
  unsigned r = v.u + 0x7fffu + ((v.u >> 16) & 1u);   // RNE
  return (short)(r >> 16);
}

// ---- Stage 1: one pass over N, bucket (ent_bits<<32)|idx per class ----
__global__ __launch_bounds__(256) void scan_classes(
    const float* __restrict__ ent, const int* __restrict__ y_hat,
    u64* __restrict__ bucket, int* __restrict__ cnt, int N)
{
  int i = blockIdx.x * 256 + threadIdx.x;
  if (i >= N) return;
  int c = y_hat[i];
  unsigned eb = __float_as_uint(ent[i]);
  u64 key = ((u64)eb << 32) | (unsigned)i;
  int p = atomicAdd(&cnt[c], 1);
  if (p < BCAP) bucket[(size_t)c * BCAP + p] = key;
}

// ---- Stage 2: per-class select + normalized-row sum, emit FRAGMENT-PACKED W ----
// Packed: frag(kt 0..15, ct 0..23) of 1024B; lane = fq*16+fr holds
// W[col = ct*16+fr][k = kt*32+fq*8+j], j=0..7. One dwordx4 wave-load = one frag.
__global__ __launch_bounds__(512) void select_accum(
    const float* __restrict__ supports, const u64* __restrict__ bucket,
    const int* __restrict__ cnt, const int* __restrict__ fKp,
    short* __restrict__ Wp)
{
  const int c = blockIdx.x;
  const int tid = threadIdx.x;
  const int lane = tid & 63, w = tid >> 6;
  __shared__ u64   s_key[BCAP];
  __shared__ int   s_selidx[BCAP];
  __shared__ int   s_nsel;
  __shared__ float s_part[8][DIM];   // 16 KB
  __shared__ float s_red[8];
  if (tid == 0) s_nsel = 0;
  const int S = (c < NCLS) ? min(cnt[c], BCAP) : 0;
  const int K = fKp[0];
  for (int e = tid; e < S; e += 512) s_key[e] = bucket[(size_t)c * BCAP + e];
  __syncthreads();
  for (int e = tid; e < S; e += 512) {
    u64 ke = s_key[e];
    int r = 0;
    for (int j = 0; j < S; ++j) r += (s_key[j] < ke) ? 1 : 0;
    if (r < K) { int p = atomicAdd(&s_nsel, 1); s_selidx[p] = (int)(unsigned)(ke & 0xffffffffull); }
  }
  __syncthreads();
  const int nsel = s_nsel;
  f32x4 p0 = {0.f,0.f,0.f,0.f}, p1 = {0.f,0.f,0.f,0.f};
  for (int e0 = w; e0 < nsel; e0 += 16) {
    const int e1 = e0 + 8;
    const bool h1 = (e1 < nsel);
    const f32x4* r0 = (const f32x4*)(supports + (size_t)s_selidx[e0] * DIM);
    f32x4 a0 = r0[lane], a1 = r0[lane + 64];
    f32x4 b0 = {0.f,0.f,0.f,0.f}, b1 = {0.f,0.f,0.f,0.f};
    if (h1) {
      const f32x4* r1 = (const f32x4*)(supports + (size_t)s_selidx[e1] * DIM);
      b0 = r1[lane]; b1 = r1[lane + 64];
    }
    float s0 = 0.f, s1 = 0.f;
#pragma unroll
    for (int j = 0; j < 4; ++j) {
      s0 = fmaf(a0[j], a0[j], s0); s0 = fmaf(a1[j], a1[j], s0);
      s1 = fmaf(b0[j], b0[j], s1); s1 = fmaf(b1[j], b1[j], s1);
    }
#pragma unroll
    for (int off = 32; off; off >>= 1) { s0 += __shfl_xor(s0, off); s1 += __shfl_xor(s1, off); }
    float c0 = 1.f / fmaxf(sqrtf(s0), 1e-12f);
    float c1 = 1.f / fmaxf(sqrtf(s1), 1e-12f);
#pragma unroll
    for (int j = 0; j < 4; ++j) { p0[j] = fmaf(a0[j], c0, p0[j]); p1[j] = fmaf(a1[j], c0, p1[j]); }
    if (h1) {
#pragma unroll
      for (int j = 0; j < 4; ++j) { p0[j] = fmaf(b0[j], c1, p0[j]); p1[j] = fmaf(b1[j], c1, p1[j]); }
    }
  }
  *(f32x4*)&s_part[w][lane * 4]       = p0;
  *(f32x4*)&s_part[w][256 + lane * 4] = p1;
  __syncthreads();
  float acc = 0.f;
#pragma unroll
  for (int ww = 0; ww < 8; ++ww) acc += s_part[ww][tid];
  float sq = acc * acc;
#pragma unroll
  for (int off = 32; off; off >>= 1) sq += __shfl_xor(sq, off);
  if (lane == 0) s_red[w] = sq;
  __syncthreads();
  float tot = 0.f;
#pragma unroll
  for (int ww = 0; ww < 8; ++ww) tot += s_red[ww];
  float sc = 1.f / fmaxf(sqrtf(tot), 1e-12f);
  {
    const int k = tid;
    const int kt = k >> 5, fq = (k >> 3) & 3, j = k & 7;
    const int ct = c >> 4, fr = c & 15;
    const size_t pos = (size_t)(kt * 24 + ct) * 512 + fq * 128 + fr * 8 + j;
    Wp[pos] = f2bf(acc * sc);
  }
}

// ---- Kernel B: out[M,345] = z[M,512] @ W ----
// A: staged ONCE per block (64 rows x full K=512, bf16, 64KB LDS, slot-XOR
// swizzle), lane-contiguous global reads, converted during staging.
// B: fragment-packed Wp from L2 (contiguous 1KB wave-loads), distance-1
// prefetch. Main loop: ZERO barriers, 16 steps x {6 B-loads + 2 ds_read_b128
// + 12 MFMA}. 8 waves = 2 M-halves x 4 col-groups. Epilogue: LDS C-blob.
__global__ __launch_bounds__(512, 4) void gemm_zw(
    const float* __restrict__ z, const short* __restrict__ Wp,
    float* __restrict__ out)
{
  __shared__ __align__(16) char lds[65536];      // A: 64 rows x 512 bf16
  const int tid  = threadIdx.x;
  const int lane = tid & 63;
  const int w    = tid >> 6;                     // wave 0..7
  const int g    = w & 3;                        // col group (96 cols)
  const int mh   = w >> 2;                       // M-half (32 rows)
  const int fr   = lane & 15, fq = lane >> 4;
  const int Mbase = blockIdx.x * 64;

  // ---- stage A: wave w stages rows {i*8+w}, one row = 2 contiguous 1KB loads ----
#pragma unroll
  for (int i = 0; i < 8; ++i) {
    const int row = i * 8 + w;
    const char* src = (const char*)(z + (size_t)(Mbase + row) * DIM);
    f32x4 v0 = *(const f32x4*)(src + lane * 16);           // k = lane*4..+3
    f32x4 v1 = *(const f32x4*)(src + 1024 + lane * 16);    // k = 256+lane*4..+3
    s16x4 b0, b1;
#pragma unroll
    for (int j = 0; j < 4; ++j) { b0[j] = f2bf(v0[j]); b1[j] = f2bf(v1[j]); }
    const unsigned so = ((unsigned)(lane >> 1) ^ ((unsigned)row & 7)) * 16 + (lane & 1) * 8;
    *(s16x4*)(lds + row * 1024 + so)       = b0;
    *(s16x4*)(lds + row * 1024 + 512 + so) = b1;
  }
  __syncthreads();                               // the ONLY pre-epilogue barrier

  // B pointers: frag(kt, ct = g*6+nt) at (kt*24+ct)*1024 + lane*16
  const char* pb = (const char*)Wp + (size_t)g * 6 * 1024 + (size_t)lane * 16;

  // A fragment addressing: row = mh*32 + mt*16 + fr; slot = (t*4+fq) ^ (row&7)
  const int arow[2] = { mh * 32 + fr, mh * 32 + 16 + fr };

  f32x4 acc[2][6];
#pragma unroll
  for (int mt = 0; mt < 2; ++mt)
#pragma unroll
    for (int nt = 0; nt < 6; ++nt) acc[mt][nt] = f32x4{0.f, 0.f, 0.f, 0.f};

  s16x8 B0[6], B1[6];
#pragma unroll
  for (int nt = 0; nt < 6; ++nt) B0[nt] = *(const s16x8*)(pb + nt * 1024);

#pragma unroll
  for (int t = 0; t < 16; ++t) {
    if (t < 15) {                                // prefetch next K-step's B frags
#pragma unroll
      for (int nt = 0; nt < 6; ++nt)
        B1[nt] = *(const s16x8*)(pb + (size_t)(t + 1) * 24576 + nt * 1024);
    }
    s16x8 af[2];
#pragma unroll
    for (int mt = 0; mt < 2; ++mt) {
      const unsigned slot = ((unsigned)(t * 4) + fq) ^ ((unsigned)arow[mt] & 7);
      af[mt] = *(const s16x8*)(lds + arow[mt] * 1024 + slot * 16);
    }
    __builtin_amdgcn_s_setprio(1);
#pragma unroll
    for (int nt = 0; nt < 6; ++nt)
#pragma unroll
      for (int mt = 0; mt < 2; ++mt)
        acc[mt][nt] = __builtin_amdgcn_mfma_f32_16x16x32_bf16(B0[nt], af[mt], acc[mt][nt], 0, 0, 0);
    __builtin_amdgcn_s_setprio(0);
    if (t < 15) {
#pragma unroll
      for (int nt = 0; nt < 6; ++nt) B0[nt] = B1[nt];
    }
  }

  // ---- epilogue: two 32-row halves through the LDS C-blob ----
#pragma unroll
  for (int h = 0; h < 2; ++h) {
    __syncthreads();                   // h=0: A reads done; h=1: copy done
    if (mh == h) {
#pragma unroll
      for (int mt = 0; mt < 2; ++mt) {
        const int rl = mt * 16 + fr;   // local row 0..31
#pragma unroll
        for (int nt = 0; nt < 6; ++nt) {
          const int colb = g * 96 + nt * 16 + fq * 4;
#pragma unroll
          for (int j = 0; j < 4; ++j) {
            const int col = colb + j;
            if (col < NCLS)
              *(float*)(lds + (((size_t)rl * NCLS + col) << 2)) = acc[mt][nt][j];
          }
        }
      }
    }
    __syncthreads();
    // flat coalesced copy: 32*345*4 = 44160 B = 2760 x 16B
    char* dst = (char*)(out + (size_t)(Mbase + h * 32) * NCLS);
    for (int c = tid; c < 2760; c += 512) {
      f32x4 v = *(const f32x4*)(lds + c * 16);
      *(f32x4*)(dst + c * 16) = v;
    }
  }
}

extern "C" void kernel_launch(void* const* d_in, const int* in_sizes, int n_in,
                              void* d_out, int out_size, void* d_ws, size_t ws_size,
                              hipStream_t stream) {
  const float* z        = (const float*)d_in[0];
  const float* supports = (const float*)d_in[1];
  const float* ent      = (const float*)d_in[2];
  const int*   y_hat    = (const int*)d_in[3];
  const int*   fK       = (const int*)d_in[4];
  float* out = (float*)d_out;
  short* Wp  = (short*)d_ws;           // fragment-packed W, 384 KB
  const int N = in_sizes[2];
  const int M = in_sizes[0] / DIM;

  const size_t offC = (size_t)CPAD * DIM * 2;          // 393216
  const size_t offB = offC + 2048;
  int* cnt    = (int*)((char*)d_ws + offC);
  u64* bucket = (u64*)((char*)d_ws + offB);
  hipMemsetAsync(cnt, 0, CPAD * sizeof(int), stream);
  scan_classes<<<dim3((N + 255) / 256), dim3(256), 0, stream>>>(ent, y_hat, bucket, cnt, N);
  select_accum<<<dim3(CPAD), dim3(512), 0, stream>>>(supports, bucket, cnt, fK, Wp);
  gemm_zw<<<dim3(M / 64), dim3(512), 0, stream>>>(z, Wp, out);
}